// Round 4
// baseline (385.412 us; speedup 1.0000x reference)
//
#include <hip/hip_runtime.h>
#include <hip/hip_bf16.h>

#define FEAT 1024
#define EMBED 128
#define CAP 64          // per-node bucket capacity (Poisson mean deg = 16)
#define OVF_CAP 4096    // overflow list capacity

// GEMM chunking: chunk = 64 feats (2 k-steps of 32), 16 chunks total
#define NCH 16
#define A_BYTES 32768   // 128 rows x 256 B per chunk
#define B_BYTES 16384   // 2 k-steps x 8 frags x 64 lanes x 16 B
#define BUF_BYTES 49152 // A + B
#define NBUF 3          // triple buffer -> 147456 B LDS, 1 block/CU

typedef __attribute__((ext_vector_type(8))) short short8;
typedef __attribute__((ext_vector_type(4))) float floatx4;

__device__ inline ushort f2bf(float f) {
    __hip_bfloat16 h = __float2bfloat16(f);
    return *reinterpret_cast<ushort*>(&h);
}
__device__ inline float bfbits_lo(uint u) {        // low 16 bits as bf16 -> f32
    uint v = u << 16; return *reinterpret_cast<float*>(&v);
}
__device__ inline float bfbits_hi(uint u) {        // high 16 bits as bf16 -> f32
    uint v = u & 0xffff0000u; return *reinterpret_cast<float*>(&v);
}

// async 16B global -> LDS (wave-uniform LDS base; HW adds lane*16; global src per-lane)
__device__ inline void async_copy16(const void* g, void* l) {
    __builtin_amdgcn_global_load_lds(
        (const __attribute__((address_space(1))) void*)g,
        (__attribute__((address_space(3))) void*)l, 16, 0, 0);
}

// --- kernel 1: W fp32 -> bf16, swizzled into MFMA-fragment-linear order ------
// wbs[((s*8 + t)*64 + lane)*8 + j] = bf16(W[t*16 + (lane&15)][s*32 + (lane>>4)*8 + j])
__global__ void swizzle_weight_kernel(const float* __restrict__ w,
                                      ushort* __restrict__ wbs) {
    int gid = blockIdx.x * blockDim.x + threadIdx.x;   // 16384 threads
    int l = gid & 63;
    int t = (gid >> 6) & 7;
    int s = gid >> 9;
    int row = t * 16 + (l & 15);
    int col = s * 32 + (l >> 4) * 8;
    const float* src = w + (size_t)row * FEAT + col;
    float4 v0 = *(const float4*)(src);
    float4 v1 = *(const float4*)(src + 4);
    short8 o;
    o[0] = f2bf(v0.x); o[1] = f2bf(v0.y); o[2] = f2bf(v0.z); o[3] = f2bf(v0.w);
    o[4] = f2bf(v1.x); o[5] = f2bf(v1.y); o[6] = f2bf(v1.z); o[7] = f2bf(v1.w);
    *(short8*)(wbs + (size_t)gid * 8) = o;
}

// --- kernel 2: merged [GEMM h = x@W^T, full DMA pipeline] + [edge bucketing] --
// GEMM role: 4 waves x 32 rows. BOTH A (x rows) and B (swizzled W) are staged
// via global_load_lds (no VGPR round-trip, deep outstanding bytes): chunk =
// 2 k-steps, TRIPLE-buffered, raw s_barrier + counted vmcnt(24) so two chunk
// DMAs (48 KB/CU) stay in flight across barriers -> Little's-law saturation
// of HBM (need ~9 KB/CU). A LDS rows are stride-256B (16-way bank conflict),
// fixed by pre-swizzling the DMA *source* with ^(row&7) on the 16B slot and
// applying the same XOR on the ds_read side (involution).
__launch_bounds__(256, 1)
__global__ void gemm_bucket_kernel(const float* __restrict__ x,
                                   const ushort* __restrict__ wbs,
                                   ushort* __restrict__ hb, int n_nodes,
                                   const int* __restrict__ adj_row,
                                   const int* __restrict__ adj_col,
                                   const float* __restrict__ adj_vals,
                                   int* __restrict__ cnt,
                                   int2* __restrict__ bucket,
                                   int* __restrict__ ovf_cnt,
                                   int* __restrict__ ovf_list,
                                   int n_edges, int gemm_blocks, int bucket_blocks) {
    __shared__ __align__(16) char lds[NBUF * BUF_BYTES];   // 147456 B

    if (blockIdx.x >= gemm_blocks) {
        // ---------------- bucket-fill role (grid-stride) ----------------
        int stride = bucket_blocks * 256;
        for (int e = (blockIdx.x - gemm_blocks) * 256 + threadIdx.x;
             e < n_edges; e += stride) {
            int r = adj_row[e];
            int slot = atomicAdd(&cnt[r], 1);
            if (slot < CAP) {
                bucket[(size_t)r * CAP + slot] =
                    make_int2(adj_col[e], __float_as_int(adj_vals[e]));
            } else {
                int oi = atomicAdd(ovf_cnt, 1);
                if (oi < OVF_CAP) ovf_list[oi] = e;
            }
        }
        return;
    }

    // ---------------- GEMM role ----------------
    const int lane = threadIdx.x & 63;
    const int wave = threadIdx.x >> 6;
    const int q    = lane >> 4;
    const int m    = lane & 15;
    const int base = blockIdx.x * 128 + wave * 32;
    const char* xb  = (const char*)x;
    const char* wbb = (const char*)wbs;

    // per-lane A DMA source offsets (8 instrs/chunk, wave-private 8 KB slice).
    // LDS (row r, slot lane&15) receives global (row, slot ^ (r&7)) -> read
    // side XORs the same, so banks spread 8-way (2-way residual = free).
    size_t aoff[8];
#pragma unroll
    for (int k = 0; k < 8; ++k) {
        int r   = k * 4 + (lane >> 4);           // row-in-wave 0..31
        int row = base + r;
        if (row >= n_nodes) row = n_nodes - 1;
        int j = (lane & 15) ^ (r & 7);           // pre-swizzled 16B slot
        aoff[k] = (size_t)row * (FEAT * 4) + (size_t)j * 16;
    }

#define STAGE(c_) do {                                                        \
        char* buf_ = lds + ((c_) % NBUF) * BUF_BYTES;                         \
        char* Aw_  = buf_ + wave * 8192;                                      \
        _Pragma("unroll")                                                     \
        for (int k = 0; k < 8; ++k)                                           \
            async_copy16(xb + aoff[k] + (size_t)(c_) * 256, Aw_ + k * 1024);  \
        const char* bs_ = wbb + (size_t)(c_) * B_BYTES + wave * 1024 + lane * 16; \
        char* Bd_ = buf_ + A_BYTES + wave * 1024;                             \
        _Pragma("unroll")                                                     \
        for (int k = 0; k < 4; ++k)                                           \
            async_copy16(bs_ + k * 4096, Bd_ + k * 4096);                     \
    } while (0)

    // prologue: 3 chunks in flight (36 DMA instrs/wave)
    STAGE(0); STAGE(1); STAGE(2);

    floatx4 acc[2][8];
#pragma unroll
    for (int rf = 0; rf < 2; ++rf)
#pragma unroll
        for (int t = 0; t < 8; ++t) acc[rf][t] = (floatx4)(0.0f);

    const int sw = (m & 7);                      // read-side swizzle key
    for (int c = 0; c < NCH; ++c) {
        // wait for OWN chunk-c DMA (12 instrs/chunk/wave in flight behind it)
        if (c <= NCH - 3)      asm volatile("s_waitcnt vmcnt(24)" ::: "memory");
        else if (c == NCH - 2) asm volatile("s_waitcnt vmcnt(12)" ::: "memory");
        else                   asm volatile("s_waitcnt vmcnt(0)"  ::: "memory");
        __builtin_amdgcn_sched_barrier(0);
        __builtin_amdgcn_s_barrier();            // all waves' chunk-c landed
        __builtin_amdgcn_sched_barrier(0);

        const char* buf = lds + (c % NBUF) * BUF_BYTES;
        const char* Aw  = buf + wave * 8192;
        const char* Bb  = buf + A_BYTES;
#pragma unroll
        for (int s01 = 0; s01 < 2; ++s01) {
            int slot0 = s01 * 8 + q * 2;
            float4 a0l = *(const float4*)(Aw + m * 256 + ((slot0     ^ sw) * 16));
            float4 a0h = *(const float4*)(Aw + m * 256 + (((slot0+1) ^ sw) * 16));
            float4 a1l = *(const float4*)(Aw + (m+16) * 256 + ((slot0     ^ sw) * 16));
            float4 a1h = *(const float4*)(Aw + (m+16) * 256 + (((slot0+1) ^ sw) * 16));

            const char* bsrc = Bb + s01 * 8192 + lane * 16;
            short8 bf[8];
#pragma unroll
            for (int t = 0; t < 8; ++t) bf[t] = *(const short8*)(bsrc + t * 1024);

            short8 af0, af1;
            af0[0] = f2bf(a0l.x); af0[1] = f2bf(a0l.y);
            af0[2] = f2bf(a0l.z); af0[3] = f2bf(a0l.w);
            af0[4] = f2bf(a0h.x); af0[5] = f2bf(a0h.y);
            af0[6] = f2bf(a0h.z); af0[7] = f2bf(a0h.w);
            af1[0] = f2bf(a1l.x); af1[1] = f2bf(a1l.y);
            af1[2] = f2bf(a1l.z); af1[3] = f2bf(a1l.w);
            af1[4] = f2bf(a1h.x); af1[5] = f2bf(a1h.y);
            af1[6] = f2bf(a1h.z); af1[7] = f2bf(a1h.w);

#pragma unroll
            for (int t = 0; t < 8; ++t) {
                acc[0][t] = __builtin_amdgcn_mfma_f32_16x16x32_bf16(af0, bf[t], acc[0][t], 0, 0, 0);
                acc[1][t] = __builtin_amdgcn_mfma_f32_16x16x32_bf16(af1, bf[t], acc[1][t], 0, 0, 0);
            }
        }

        __builtin_amdgcn_s_barrier();            // all waves done reading buf[c%3]
        __builtin_amdgcn_sched_barrier(0);
        if (c <= NCH - 4) STAGE(c + 3);          // refill just-freed buffer
    }
#undef STAGE

#pragma unroll
    for (int rf = 0; rf < 2; ++rf) {
#pragma unroll
        for (int t = 0; t < 8; ++t) {
#pragma unroll
            for (int r = 0; r < 4; ++r) {
                int rr = base + rf * 16 + q * 4 + r;
                if (rr < n_nodes)
                    hb[(size_t)rr * EMBED + t * 16 + m] = f2bf(acc[rf][t][r]);
            }
        }
    }
}

// --- kernel 3: per-node gather-accumulate, batch-16 pipelined ----------------
// 4 nodes per 256-thread block (1 wave per node). Bucket-entry loads are
// decoupled from the h gathers: all 8 int4s of a 16-edge batch are issued up
// front, the 16 gathers go in flight together, and the NEXT batch's bucket
// loads are issued under the FMAs -> serial bucket->gather chain broken.
__launch_bounds__(256)
__global__ void gather_kernel(const int* __restrict__ cnt,
                              const int2* __restrict__ bucket,
                              const ushort* __restrict__ hb,
                              const int* __restrict__ ovf_cnt,
                              const int* __restrict__ ovf_list,
                              const int* __restrict__ adj_row,
                              const int* __restrict__ adj_col,
                              const float* __restrict__ adj_vals,
                              float* __restrict__ out, int n_nodes) {
    int node = __builtin_amdgcn_readfirstlane(blockIdx.x * 4 + (threadIdx.x >> 6));
    if (node >= n_nodes) return;
    int lane = threadIdx.x & 63;
    int c_raw = cnt[node];
    int c = c_raw > CAP ? CAP : c_raw;
    const int2* bp = bucket + (size_t)node * CAP;
    const ushort* hl = hb + lane * 2;       // per-lane column offset (bf16x2)

    float accx = 0.0f, accy = 0.0f;
    int nb = c >> 4;                        // full 16-edge batches
    if (nb > 0) {
        int4 eb[8];
#pragma unroll
        for (int i = 0; i < 8; ++i) eb[i] = *(const int4*)(bp + i * 2);
        for (int b = 0; b < nb; ++b) {
            uint u[16]; float wv[16];
#pragma unroll
            for (int i = 0; i < 8; ++i) {
                u[2*i]   = *(const uint*)(hl + (size_t)eb[i].x * EMBED);
                u[2*i+1] = *(const uint*)(hl + (size_t)eb[i].z * EMBED);
                wv[2*i]   = __int_as_float(eb[i].y);
                wv[2*i+1] = __int_as_float(eb[i].w);
            }
            if (b + 1 < nb) {               // prefetch next batch's bucket entries
#pragma unroll
                for (int i = 0; i < 8; ++i)
                    eb[i] = *(const int4*)(bp + (b + 1) * 16 + i * 2);
            }
#pragma unroll
            for (int i = 0; i < 16; ++i) {
                accx = fmaf(wv[i], bfbits_lo(u[i]), accx);
                accy = fmaf(wv[i], bfbits_hi(u[i]), accy);
            }
        }
    }
    int j = nb * 16;
    for (; j + 2 <= c; j += 2) {
        int4 e01 = *(const int4*)(bp + j);
        uint u0 = *(const uint*)(hl + (size_t)e01.x * EMBED);
        uint u1 = *(const uint*)(hl + (size_t)e01.z * EMBED);
        float w0 = __int_as_float(e01.y), w1 = __int_as_float(e01.w);
        accx = fmaf(w0, bfbits_lo(u0), accx);  accy = fmaf(w0, bfbits_hi(u0), accy);
        accx = fmaf(w1, bfbits_lo(u1), accx);  accy = fmaf(w1, bfbits_hi(u1), accy);
    }
    if (j < c) {
        int2 ev = bp[j];
        uint u = *(const uint*)(hl + (size_t)ev.x * EMBED);
        float w = __int_as_float(ev.y);
        accx = fmaf(w, bfbits_lo(u), accx);
        accy = fmaf(w, bfbits_hi(u), accy);
    }
    if (c_raw > CAP) {                        // inline overflow fixup (expected 0)
        int n = *ovf_cnt;
        if (n > OVF_CAP) n = OVF_CAP;
        for (int i = 0; i < n; ++i) {
            int e = ovf_list[i];
            if (adj_row[e] == node) {
                uint u = *(const uint*)(hl + (size_t)adj_col[e] * EMBED);
                float w = adj_vals[e];
                accx = fmaf(w, bfbits_lo(u), accx);
                accy = fmaf(w, bfbits_hi(u), accy);
            }
        }
    }
    *(float2*)(out + (size_t)node * EMBED + lane * 2) = make_float2(accx, accy);
}

extern "C" void kernel_launch(void* const* d_in, const int* in_sizes, int n_in,
                              void* d_out, int out_size, void* d_ws, size_t ws_size,
                              hipStream_t stream) {
    const float* x        = (const float*)d_in[0];
    const float* w        = (const float*)d_in[1];
    const int*   adj_row  = (const int*)d_in[2];
    const int*   adj_col  = (const int*)d_in[3];
    const float* adj_vals = (const float*)d_in[4];

    const int n_nodes = in_sizes[0] / FEAT;
    const int n_edges = in_sizes[2];
    float* out = (float*)d_out;

    // workspace layout (bytes):
    //   [wbs 256KB][hb n*128*2][cnt n*4][ovf_cnt 4][ovf_list][pad->16][bucket n*CAP*8]
    char* ws = (char*)d_ws;
    ushort* wbs = (ushort*)ws;
    size_t off = 262144;
    ushort* hb = (ushort*)(ws + off);
    off += (size_t)n_nodes * EMBED * sizeof(ushort);
    char* meta = ws + off;
    int* cnt      = (int*)meta;
    int* ovf_cnt  = (int*)(meta + (size_t)n_nodes * 4);
    int* ovf_list = ovf_cnt + 1;
    size_t meta_bytes = ((size_t)n_nodes * 4 + 4 + OVF_CAP * 4 + 15) & ~(size_t)15;
    int2* bucket = (int2*)(meta + meta_bytes);

    hipMemsetAsync(meta, 0, meta_bytes, stream);

    swizzle_weight_kernel<<<64, 256, 0, stream>>>(w, wbs);

    const int gemm_blocks   = (n_nodes + 127) / 128;
    const int bucket_blocks = 512;
    gemm_bucket_kernel<<<gemm_blocks + bucket_blocks, 256, 0, stream>>>(
        x, wbs, hb, n_nodes,
        adj_row, adj_col, adj_vals,
        cnt, bucket, ovf_cnt, ovf_list, n_edges, gemm_blocks, bucket_blocks);

    gather_kernel<<<(n_nodes + 3) / 4, 256, 0, stream>>>(
        cnt, bucket, hb, ovf_cnt, ovf_list, adj_row, adj_col, adj_vals,
        out, n_nodes);
}

// Round 5
// 365.150 us; speedup vs baseline: 1.0555x; 1.0555x over previous
//
#include <hip/hip_runtime.h>
#include <hip/hip_bf16.h>

#define FEAT 1024
#define EMBED 128
#define CAP 64          // per-node bucket capacity (Poisson mean deg = 16)
#define OVF_CAP 4096    // overflow list capacity

#define NCHUNK 16       // 16 chunks x 2 k-steps x 32 feats = 1024
#define B_CHUNK 16384   // B bytes per chunk: 2 ksteps x 8 frags x 64 lanes x 16 B

typedef __attribute__((ext_vector_type(8))) short short8;
typedef __attribute__((ext_vector_type(4))) float floatx4;

__device__ inline ushort f2bf(float f) {
    __hip_bfloat16 h = __float2bfloat16(f);
    return *reinterpret_cast<ushort*>(&h);
}
__device__ inline float bfbits_lo(uint u) {        // low 16 bits as bf16 -> f32
    uint v = u << 16; return *reinterpret_cast<float*>(&v);
}
__device__ inline float bfbits_hi(uint u) {        // high 16 bits as bf16 -> f32
    uint v = u & 0xffff0000u; return *reinterpret_cast<float*>(&v);
}

// async 16B global -> LDS (wave-uniform LDS base; HW adds lane*16; global src per-lane)
__device__ inline void async_copy16(const void* g, void* l) {
    __builtin_amdgcn_global_load_lds(
        (const __attribute__((address_space(1))) void*)g,
        (__attribute__((address_space(3))) void*)l, 16, 0, 0);
}

// --- kernel 1: W fp32 -> bf16, swizzled into MFMA-fragment-linear order ------
// wbs[((s*8 + t)*64 + lane)*8 + j] = bf16(W[t*16 + (lane&15)][s*32 + (lane>>4)*8 + j])
__global__ void swizzle_weight_kernel(const float* __restrict__ w,
                                      ushort* __restrict__ wbs) {
    int gid = blockIdx.x * blockDim.x + threadIdx.x;   // 16384 threads
    int l = gid & 63;
    int t = (gid >> 6) & 7;
    int s = gid >> 9;
    int row = t * 16 + (l & 15);
    int col = s * 32 + (l >> 4) * 8;
    const float* src = w + (size_t)row * FEAT + col;
    float4 v0 = *(const float4*)(src);
    float4 v1 = *(const float4*)(src + 4);
    short8 o;
    o[0] = f2bf(v0.x); o[1] = f2bf(v0.y); o[2] = f2bf(v0.z); o[3] = f2bf(v0.w);
    o[4] = f2bf(v1.x); o[5] = f2bf(v1.y); o[6] = f2bf(v1.z); o[7] = f2bf(v1.w);
    *(short8*)(wbs + (size_t)gid * 8) = o;
}

// --- kernel 2: merged [GEMM h = x@W^T] + [edge bucketing] --------------------
// GEMM role, occupancy-first: 4 waves x 16 rows = 64 rows/block, only 32 KB
// LDS (B double-buffer, chunk = 2 k-steps) + ~125 VGPR -> 3 blocks/CU =
// 12 waves/CU. Per-chunk __syncthreads drains are hidden by IMPLICIT overlap
// across the 3 independent blocks per CU (the m97/m114 mechanism) instead of
// explicit per-wave DMA depth, which round-4 showed does not convert to BW.
// A = register stream with one-chunk prefetch; B staged via global_load_lds
// (zero VGPR cost, lgkmcnt-decoupled from the A vmcnt stream).
__launch_bounds__(256, 3)
__global__ void gemm_bucket_kernel(const float* __restrict__ x,
                                   const ushort* __restrict__ wbs,
                                   ushort* __restrict__ hb, int n_nodes,
                                   const int* __restrict__ adj_row,
                                   const int* __restrict__ adj_col,
                                   const float* __restrict__ adj_vals,
                                   int* __restrict__ cnt,
                                   int2* __restrict__ bucket,
                                   int* __restrict__ ovf_cnt,
                                   int* __restrict__ ovf_list,
                                   int n_edges, int gemm_blocks, int bucket_blocks) {
    __shared__ __align__(16) char lds[2][B_CHUNK];         // 32 KB

    if (blockIdx.x >= gemm_blocks) {
        // ---------------- bucket-fill role (grid-stride) ----------------
        int stride = bucket_blocks * 256;
        for (int e = (blockIdx.x - gemm_blocks) * 256 + threadIdx.x;
             e < n_edges; e += stride) {
            int r = adj_row[e];
            int slot = atomicAdd(&cnt[r], 1);
            if (slot < CAP) {
                bucket[(size_t)r * CAP + slot] =
                    make_int2(adj_col[e], __float_as_int(adj_vals[e]));
            } else {
                int oi = atomicAdd(ovf_cnt, 1);
                if (oi < OVF_CAP) ovf_list[oi] = e;
            }
        }
        return;
    }

    // ---------------- GEMM role ----------------
    const int lane = threadIdx.x & 63;
    const int wave = threadIdx.x >> 6;
    const int q    = lane >> 4;
    const int m    = lane & 15;
    const int base = blockIdx.x * 64 + wave * 16;

    int row = base + m;
    if (row >= n_nodes) row = n_nodes - 1;
    const float* xp = x + (size_t)row * FEAT + q * 8;
    const char* wbb = (const char*)wbs;

    // stage B chunk 0 (each wave copies its 4 KB slice, 4 x 1 KB DMA instrs)
    {
        const char* bs = wbb + wave * 4096 + lane * 16;
        char* bd = lds[0] + wave * 4096;
#pragma unroll
        for (int k = 0; k < 4; ++k)
            async_copy16(bs + k * 1024, bd + k * 1024);
    }

    // A regs for chunk 0: ksteps 0,1 -> float offsets 0 and 32
    float4 A0 = *(const float4*)(xp);
    float4 A1 = *(const float4*)(xp + 4);
    float4 A2 = *(const float4*)(xp + 32);
    float4 A3 = *(const float4*)(xp + 36);

    floatx4 acc[8];
#pragma unroll
    for (int t = 0; t < 8; ++t) acc[t] = (floatx4)(0.0f);

    __syncthreads();                              // chunk-0 B landed

    for (int c = 0; c < NCHUNK; ++c) {
        const char* buf = lds[c & 1];
        float4 N0, N1, N2, N3;
        if (c + 1 < NCHUNK) {
            // stage next B chunk into the buffer freed at the LAST barrier
            const char* bs = wbb + (size_t)(c + 1) * B_CHUNK + wave * 4096 + lane * 16;
            char* bd = lds[(c + 1) & 1] + wave * 4096;
#pragma unroll
            for (int k = 0; k < 4; ++k)
                async_copy16(bs + k * 1024, bd + k * 1024);
            // prefetch next A chunk (2 k-steps = 256 B per row)
            const float* np = xp + (c + 1) * 64;
            N0 = *(const float4*)(np);
            N1 = *(const float4*)(np + 4);
            N2 = *(const float4*)(np + 32);
            N3 = *(const float4*)(np + 36);
        }
#pragma unroll
        for (int sl = 0; sl < 2; ++sl) {
            const char* bsrc = buf + sl * 8192 + lane * 16;
            short8 bf[8];
#pragma unroll
            for (int t = 0; t < 8; ++t) bf[t] = *(const short8*)(bsrc + t * 1024);

            float4 al = sl ? A2 : A0;
            float4 ah = sl ? A3 : A1;
            short8 af;
            af[0] = f2bf(al.x); af[1] = f2bf(al.y);
            af[2] = f2bf(al.z); af[3] = f2bf(al.w);
            af[4] = f2bf(ah.x); af[5] = f2bf(ah.y);
            af[6] = f2bf(ah.z); af[7] = f2bf(ah.w);

#pragma unroll
            for (int t = 0; t < 8; ++t)
                acc[t] = __builtin_amdgcn_mfma_f32_16x16x32_bf16(af, bf[t], acc[t], 0, 0, 0);
        }
        __syncthreads();                          // drains stage(c+1)+A(c+1); buf swap safe
        A0 = N0; A1 = N1; A2 = N2; A3 = N3;
    }

#pragma unroll
    for (int t = 0; t < 8; ++t) {
#pragma unroll
        for (int r = 0; r < 4; ++r) {
            int rr = base + q * 4 + r;
            if (rr < n_nodes)
                hb[(size_t)rr * EMBED + t * 16 + m] = f2bf(acc[t][r]);
        }
    }
}

// --- kernel 3: per-node gather-accumulate, batched (16/8/2/1) ----------------
// 4 nodes per 256-thread block (1 wave per node). Bucket loads decoupled from
// h gathers; batch-8 middle tier halves the serial dependent-latency tail.
__launch_bounds__(256)
__global__ void gather_kernel(const int* __restrict__ cnt,
                              const int2* __restrict__ bucket,
                              const ushort* __restrict__ hb,
                              const int* __restrict__ ovf_cnt,
                              const int* __restrict__ ovf_list,
                              const int* __restrict__ adj_row,
                              const int* __restrict__ adj_col,
                              const float* __restrict__ adj_vals,
                              float* __restrict__ out, int n_nodes) {
    int node = __builtin_amdgcn_readfirstlane(blockIdx.x * 4 + (threadIdx.x >> 6));
    if (node >= n_nodes) return;
    int lane = threadIdx.x & 63;
    int c_raw = cnt[node];
    int c = c_raw > CAP ? CAP : c_raw;
    const int2* bp = bucket + (size_t)node * CAP;
    const ushort* hl = hb + lane * 2;       // per-lane column offset (bf16x2)

    float accx = 0.0f, accy = 0.0f;
    int nb = c >> 4;                        // full 16-edge batches
    if (nb > 0) {
        int4 eb[8];
#pragma unroll
        for (int i = 0; i < 8; ++i) eb[i] = *(const int4*)(bp + i * 2);
        for (int b = 0; b < nb; ++b) {
            uint u[16]; float wv[16];
#pragma unroll
            for (int i = 0; i < 8; ++i) {
                u[2*i]   = *(const uint*)(hl + (size_t)eb[i].x * EMBED);
                u[2*i+1] = *(const uint*)(hl + (size_t)eb[i].z * EMBED);
                wv[2*i]   = __int_as_float(eb[i].y);
                wv[2*i+1] = __int_as_float(eb[i].w);
            }
            if (b + 1 < nb) {               // prefetch next batch's bucket entries
#pragma unroll
                for (int i = 0; i < 8; ++i)
                    eb[i] = *(const int4*)(bp + (b + 1) * 16 + i * 2);
            }
#pragma unroll
            for (int i = 0; i < 16; ++i) {
                accx = fmaf(wv[i], bfbits_lo(u[i]), accx);
                accy = fmaf(wv[i], bfbits_hi(u[i]), accy);
            }
        }
    }
    int j = nb * 16;
    if (j + 8 <= c) {                       // batch-8 middle tier
        int4 eb[4];
#pragma unroll
        for (int i = 0; i < 4; ++i) eb[i] = *(const int4*)(bp + j + i * 2);
        uint u[8]; float wv[8];
#pragma unroll
        for (int i = 0; i < 4; ++i) {
            u[2*i]   = *(const uint*)(hl + (size_t)eb[i].x * EMBED);
            u[2*i+1] = *(const uint*)(hl + (size_t)eb[i].z * EMBED);
            wv[2*i]   = __int_as_float(eb[i].y);
            wv[2*i+1] = __int_as_float(eb[i].w);
        }
#pragma unroll
        for (int i = 0; i < 8; ++i) {
            accx = fmaf(wv[i], bfbits_lo(u[i]), accx);
            accy = fmaf(wv[i], bfbits_hi(u[i]), accy);
        }
        j += 8;
    }
    for (; j + 2 <= c; j += 2) {
        int4 e01 = *(const int4*)(bp + j);
        uint u0 = *(const uint*)(hl + (size_t)e01.x * EMBED);
        uint u1 = *(const uint*)(hl + (size_t)e01.z * EMBED);
        float w0 = __int_as_float(e01.y), w1 = __int_as_float(e01.w);
        accx = fmaf(w0, bfbits_lo(u0), accx);  accy = fmaf(w0, bfbits_hi(u0), accy);
        accx = fmaf(w1, bfbits_lo(u1), accx);  accy = fmaf(w1, bfbits_hi(u1), accy);
    }
    if (j < c) {
        int2 ev = bp[j];
        uint u = *(const uint*)(hl + (size_t)ev.x * EMBED);
        float w = __int_as_float(ev.y);
        accx = fmaf(w, bfbits_lo(u), accx);
        accy = fmaf(w, bfbits_hi(u), accy);
    }
    if (c_raw > CAP) {                        // inline overflow fixup (expected 0)
        int n = *ovf_cnt;
        if (n > OVF_CAP) n = OVF_CAP;
        for (int i = 0; i < n; ++i) {
            int e = ovf_list[i];
            if (adj_row[e] == node) {
                uint u = *(const uint*)(hl + (size_t)adj_col[e] * EMBED);
                float w = adj_vals[e];
                accx = fmaf(w, bfbits_lo(u), accx);
                accy = fmaf(w, bfbits_hi(u), accy);
            }
        }
    }
    *(float2*)(out + (size_t)node * EMBED + lane * 2) = make_float2(accx, accy);
}

extern "C" void kernel_launch(void* const* d_in, const int* in_sizes, int n_in,
                              void* d_out, int out_size, void* d_ws, size_t ws_size,
                              hipStream_t stream) {
    const float* x        = (const float*)d_in[0];
    const float* w        = (const float*)d_in[1];
    const int*   adj_row  = (const int*)d_in[2];
    const int*   adj_col  = (const int*)d_in[3];
    const float* adj_vals = (const float*)d_in[4];

    const int n_nodes = in_sizes[0] / FEAT;
    const int n_edges = in_sizes[2];
    float* out = (float*)d_out;

    // workspace layout (bytes):
    //   [wbs 256KB][hb n*128*2][cnt n*4][ovf_cnt 4][ovf_list][pad->16][bucket n*CAP*8]
    char* ws = (char*)d_ws;
    ushort* wbs = (ushort*)ws;
    size_t off = 262144;
    ushort* hb = (ushort*)(ws + off);
    off += (size_t)n_nodes * EMBED * sizeof(ushort);
    char* meta = ws + off;
    int* cnt      = (int*)meta;
    int* ovf_cnt  = (int*)(meta + (size_t)n_nodes * 4);
    int* ovf_list = ovf_cnt + 1;
    size_t meta_bytes = ((size_t)n_nodes * 4 + 4 + OVF_CAP * 4 + 15) & ~(size_t)15;
    int2* bucket = (int2*)(meta + meta_bytes);

    hipMemsetAsync(meta, 0, meta_bytes, stream);

    swizzle_weight_kernel<<<64, 256, 0, stream>>>(w, wbs);

    const int gemm_blocks   = (n_nodes + 63) / 64;
    const int bucket_blocks = 1024;
    gemm_bucket_kernel<<<gemm_blocks + bucket_blocks, 256, 0, stream>>>(
        x, wbs, hb, n_nodes,
        adj_row, adj_col, adj_vals,
        cnt, bucket, ovf_cnt, ovf_list, n_edges, gemm_blocks, bucket_blocks);

    gather_kernel<<<(n_nodes + 3) / 4, 256, 0, stream>>>(
        cnt, bucket, hb, ovf_cnt, ovf_list, adj_row, adj_col, adj_vals,
        out, n_nodes);
}